// Round 12
// baseline (718.231 us; speedup 1.0000x reference)
//
#include <hip/hip_runtime.h>
#include <hip/hip_bf16.h>

#define N_NODES 50000
#define N_EDGES 800000
#define FD 128
#define N_GRAPHS 256
#define NPART 6250   // N_NODES / 8 (nodes per XCD partition)

typedef unsigned short u16;
typedef short bf16x8 __attribute__((ext_vector_type(8)));
typedef float f32x4 __attribute__((ext_vector_type(4)));

__device__ __forceinline__ u16 f2bf(float v) {
    __hip_bfloat16 h = __float2bfloat16(v);
    union { __hip_bfloat16 hh; u16 u; } c; c.hh = h; return c.u;
}
__device__ __forceinline__ float bf2f(u16 r) {
    return __uint_as_float(((unsigned int)r) << 16);
}

// ---------------------------------------------------------------- CSR build (XCD-partitioned)
__global__ __launch_bounds__(256) void count_deg_part_k(const int* __restrict__ src,
                                                        int* __restrict__ cnt, int E) {
    int part = blockIdx.x & 7;
    int lo = part * NPART, hi = lo + NPART;
    int stride = (gridDim.x >> 3) * 256;
    for (int e = (blockIdx.x >> 3) * 256 + threadIdx.x; e < E; e += stride) {
        int s = src[e];
        if (s >= lo && s < hi) atomicAdd(&cnt[s], 1);
    }
}

__global__ __launch_bounds__(256) void fill_csr_part_k(const int* __restrict__ src,
                                                       const int* __restrict__ dst,
                                                       int* __restrict__ cur,
                                                       int* __restrict__ edst, int E) {
    int part = blockIdx.x & 7;
    int lo = part * NPART, hi = lo + NPART;
    int stride = (gridDim.x >> 3) * 256;
    for (int e = (blockIdx.x >> 3) * 256 + threadIdx.x; e < E; e += stride) {
        int s = src[e];
        if (s >= lo && s < hi) {
            int p = atomicAdd(&cur[s], 1);
            edst[p] = dst[e];
        }
    }
}

// per-256-chunk sums; block 0 also zeroes bnbuf (512 f) and pooled (32768 f)
__global__ __launch_bounds__(256) void scan1_k(const int* __restrict__ cnt,
                                               int* __restrict__ bsum, int M,
                                               float* __restrict__ bnbuf,
                                               float* __restrict__ pooled) {
    int i = blockIdx.x * 256 + threadIdx.x;
    int v = (i < M) ? cnt[i] : 0;
    __shared__ int l[256];
    l[threadIdx.x] = v;
    __syncthreads();
    for (int s = 128; s > 0; s >>= 1) {
        if (threadIdx.x < s) l[threadIdx.x] += l[threadIdx.x + s];
        __syncthreads();
    }
    if (threadIdx.x == 0) bsum[blockIdx.x] = l[0];
    if (blockIdx.x == 0) {
        bnbuf[threadIdx.x] = 0.f; bnbuf[threadIdx.x + 256] = 0.f;
        for (int k = threadIdx.x; k < N_GRAPHS * FD; k += 256) pooled[k] = 0.f;
    }
}

// local exclusive scan + redundant per-block scan of raw bsum (merged scan2)
__global__ __launch_bounds__(256) void scan3_k(const int* __restrict__ cnt,
                                               const int* __restrict__ bsum,
                                               int* __restrict__ offs,
                                               int* __restrict__ cur, int M, int NB) {
    int i = blockIdx.x * 256 + threadIdx.x;
    int tid = threadIdx.x;
    __shared__ int bs[256];
    bs[tid] = (tid < NB) ? bsum[tid] : 0;
    __syncthreads();
    for (int off = 1; off < 256; off <<= 1) {
        int t = (tid >= off) ? bs[tid - off] : 0;
        __syncthreads();
        bs[tid] += t;
        __syncthreads();
    }
    int base = (blockIdx.x == 0) ? 0 : bs[blockIdx.x - 1];
    int v = (i < M) ? cnt[i] : 0;
    __shared__ int l[256];
    l[tid] = v;
    __syncthreads();
    for (int off = 1; off < 256; off <<= 1) {
        int t = (tid >= off) ? l[tid - off] : 0;
        __syncthreads();
        l[tid] += t;
        __syncthreads();
    }
    int excl = l[tid] - v + base;
    if (i < M) { offs[i] = excl; cur[i] = excl; }
    if (i == M - 1) offs[M] = excl + v;
}

// ---------------------------------------------------------------- weight prep
// layer 1 (no affine): Wt[n][k] = bf16(W[k][n]); cvec = 0
__global__ __launch_bounds__(128) void wprep1_k(const float* __restrict__ W,
                                                u16* __restrict__ Wt,
                                                float* __restrict__ cvec) {
    int n = blockIdx.x, k = threadIdx.x;
    Wt[(size_t)n * FD + k] = f2bf(W[(size_t)k * FD + n]);
    if (k == 0) cvec[n] = 0.f;
}

// layers 2/3: BN finalize (redundant per block, from sums/sumsq) + weight fold
__global__ __launch_bounds__(128) void bnfw_k(const float* __restrict__ W,
                                              const float* __restrict__ sums,
                                              const float* __restrict__ sumsq,
                                              const float* __restrict__ g,
                                              const float* __restrict__ b,
                                              float invN,
                                              u16* __restrict__ Wt,
                                              float* __restrict__ cvec) {
    int n = blockIdx.x, k = threadIdx.x;
    __shared__ float scs[128], shs[128], l[128];
    float mu = sums[k] * invN;
    float var = sumsq[k] * invN - mu * mu;
    float sc = g[k] * rsqrtf(var + 1e-5f);
    scs[k] = sc;
    shs[k] = b[k] - mu * sc;
    __syncthreads();
    float w = W[(size_t)k * FD + n];
    Wt[(size_t)n * FD + k] = f2bf(scs[k] * w);
    l[k] = shs[k] * w;
    __syncthreads();
    for (int s = 64; s > 0; s >>= 1) {
        if (k < s) l[k] += l[k + s];
        __syncthreads();
    }
    if (k == 0) cvec[n] = l[0];
}

// ---------------------------------------------------------------- MFMA GEMM + dots
__global__ __launch_bounds__(256) void gemm_mfma_k(const float* __restrict__ Xf,
                                                   const u16* __restrict__ Xb,
                                                   int use_f32,
                                                   const u16* __restrict__ Wt,
                                                   const float* __restrict__ cvec,
                                                   const float* __restrict__ avec,
                                                   u16* __restrict__ Hb,
                                                   float* __restrict__ es,
                                                   float* __restrict__ ed, int M) {
    __shared__ u16 As[64][136];   // +8 pad: 2-way bank alias only
    __shared__ u16 Bs[128][136];
    __shared__ float sa_s[128], sa_d[128], cv[128];
    int tid = threadIdx.x;
    if (tid < 128) { sa_s[tid] = avec[tid]; sa_d[tid] = avec[128 + tid]; cv[tid] = cvec[tid]; }
    int row0 = blockIdx.x * 64;
    {
        int n = tid >> 1, k0 = (tid & 1) * 64;
        const uint4* s = (const uint4*)(Wt + (size_t)n * FD + k0);
#pragma unroll
        for (int u = 0; u < 8; u++) *(uint4*)&Bs[n][k0 + u * 8] = s[u];
    }
    {
        int r = tid >> 2, k0 = (tid & 3) * 32;
        int grow = row0 + r;
        if (grow < M) {
            if (use_f32) {
                const float4* s = (const float4*)(Xf + (size_t)grow * FD + k0);
#pragma unroll
                for (int u = 0; u < 8; u++) {
                    float4 v = s[u];
                    ushort4 o;
                    o.x = f2bf(v.x); o.y = f2bf(v.y); o.z = f2bf(v.z); o.w = f2bf(v.w);
                    *(ushort4*)&As[r][k0 + u * 4] = o;
                }
            } else {
                const uint4* s = (const uint4*)(Xb + (size_t)grow * FD + k0);
#pragma unroll
                for (int u = 0; u < 4; u++) *(uint4*)&As[r][k0 + u * 8] = s[u];
            }
        } else {
            uint4 z = make_uint4(0, 0, 0, 0);
#pragma unroll
            for (int u = 0; u < 4; u++) *(uint4*)&As[r][k0 + u * 8] = z;
        }
    }
    __syncthreads();

    int wave = tid >> 6, lane = tid & 63;
    int quad = lane >> 4, n16 = lane & 15;
    int rbase = wave * 16;
    f32x4 acc[8];
    f32x4 zz = {0.f, 0.f, 0.f, 0.f};
#pragma unroll
    for (int t = 0; t < 8; t++) acc[t] = zz;

#pragma unroll
    for (int kk = 0; kk < 128; kk += 32) {
        bf16x8 a = *(const bf16x8*)&As[rbase + n16][kk + quad * 8];
#pragma unroll
        for (int t = 0; t < 8; t++) {
            bf16x8 b = *(const bf16x8*)&Bs[t * 16 + n16][kk + quad * 8];
            acc[t] = __builtin_amdgcn_mfma_f32_16x16x32_bf16(a, b, acc[t], 0, 0, 0);
        }
    }

#pragma unroll
    for (int reg = 0; reg < 4; reg++) {
        int grow = row0 + rbase + quad * 4 + reg;
        float vals[8];
        float ps = 0.f, pd = 0.f;
#pragma unroll
        for (int t = 0; t < 8; t++) {
            float v = acc[t][reg] + cv[t * 16 + n16];
            vals[t] = v;
            ps += v * sa_s[t * 16 + n16];
            pd += v * sa_d[t * 16 + n16];
        }
#pragma unroll
        for (int o = 8; o > 0; o >>= 1) { ps += __shfl_xor(ps, o); pd += __shfl_xor(pd, o); }
        if (grow < M) {
            if (n16 == 0) { es[grow] = ps; ed[grow] = pd; }
#pragma unroll
            for (int t = 0; t < 8; t++)
                Hb[(size_t)grow * FD + t * 16 + n16] = f2bf(vals[t]);
        }
    }
}

// ---------------------------------------------------------------- fused aggregation
// wave per node; 4 edges per gather instruction (16 lanes x 16B per edge row);
// edge stream + ed on the scalar pipe; 2-round butterfly combine; 16-lane uint4 store.
__device__ __forceinline__ void gat4(const uint4* __restrict__ Hq, int p, int g,
                                     const int* d4, const float* w4, float* acc) {
    int dg = (g & 2) ? ((g & 1) ? d4[3] : d4[2]) : ((g & 1) ? d4[1] : d4[0]);
    float wg = (g & 2) ? ((g & 1) ? w4[3] : w4[2]) : ((g & 1) ? w4[1] : w4[0]);
    uint4 r = Hq[(size_t)dg * 16 + p];
    acc[0] += wg * __uint_as_float(r.x << 16);
    acc[1] += wg * __uint_as_float(r.x & 0xffff0000u);
    acc[2] += wg * __uint_as_float(r.y << 16);
    acc[3] += wg * __uint_as_float(r.y & 0xffff0000u);
    acc[4] += wg * __uint_as_float(r.z << 16);
    acc[5] += wg * __uint_as_float(r.z & 0xffff0000u);
    acc[6] += wg * __uint_as_float(r.w << 16);
    acc[7] += wg * __uint_as_float(r.w & 0xffff0000u);
}

__global__ __launch_bounds__(256) void agg_k(const u16* __restrict__ Hb,
                                             const float* __restrict__ es_,
                                             const float* __restrict__ ed_,
                                             const int* __restrict__ offs,
                                             const int* __restrict__ edst,
                                             u16* __restrict__ Out, int M) {
    int node = __builtin_amdgcn_readfirstlane((int)((blockIdx.x * blockDim.x + threadIdx.x) >> 6));
    int lane = threadIdx.x & 63;
    if (node >= M) return;
    int g = lane >> 4;      // edge slot 0..3
    int p = lane & 15;      // feature octet: features p*8 .. p*8+7
    int s0 = offs[node], s1 = offs[node + 1];
    float esv = es_[node];
    const uint4* Hq = (const uint4*)Hb;     // row = 16 x uint4 (256 B)
    float acc[8] = {0.f, 0.f, 0.f, 0.f, 0.f, 0.f, 0.f, 0.f};
    float rs = 0.f;
    int e = s0;
    for (; e + 8 <= s1; e += 8) {
        int d[8]; float w[8];
#pragma unroll
        for (int u = 0; u < 8; u++) d[u] = __builtin_amdgcn_readfirstlane(edst[e + u]);
#pragma unroll
        for (int u = 0; u < 8; u++) {
            float ev = esv + ed_[d[u]];
            float lr = ev > 0.f ? ev : 0.2f * ev;
            w[u] = __expf(-lr);
            rs += w[u];
        }
        gat4(Hq, p, g, d, w, acc);
        gat4(Hq, p, g, d + 4, w + 4, acc);
    }
    while (e < s1) {
        int m = s1 - e; if (m > 4) m = 4;
        int d4[4]; float w4[4];
#pragma unroll
        for (int u = 0; u < 4; u++) {
            if (u < m) {
                int dd = __builtin_amdgcn_readfirstlane(edst[e + u]);
                float ev = esv + ed_[dd];
                float lr = ev > 0.f ? ev : 0.2f * ev;
                d4[u] = dd;
                w4[u] = __expf(-lr);
                rs += w4[u];
            } else { d4[u] = d4[0]; w4[u] = 0.f; }
        }
        gat4(Hq, p, g, d4, w4, acc);
        e += m;
    }
    // combine the 4 edge-groups (lanes xor 16, 32 hold same features)
#pragma unroll
    for (int o = 16; o < 64; o <<= 1)
#pragma unroll
        for (int f = 0; f < 8; f++) acc[f] += __shfl_xor(acc[f], o);
    float inv = 1.f / (rs + 1e-16f);
    if (g == 0) {
        uint4 o4;
        unsigned int* po = (unsigned int*)&o4;
#pragma unroll
        for (int q = 0; q < 4; q++) {
            float v0 = acc[2 * q] * inv, v1 = acc[2 * q + 1] * inv;
            v0 = v0 > 0.f ? v0 : (__expf(v0) - 1.f);   // elu
            v1 = v1 > 0.f ? v1 : (__expf(v1) - 1.f);
            po[q] = ((unsigned int)f2bf(v1) << 16) | f2bf(v0);
        }
        ((uint4*)Out)[(size_t)node * 16 + p] = o4;
    }
}

// ---------------------------------------------------------------- BN stats (bf16 input)
__global__ void bnstats_b_k(const u16* __restrict__ Xb, float* __restrict__ sums,
                            float* __restrict__ sumsq, int M) {
    int f = threadIdx.x & 127;
    int half = threadIdx.x >> 7;
    float s1 = 0.f, s2 = 0.f;
    for (int r = blockIdx.x * 2 + half; r < M; r += gridDim.x * 2) {
        float v = bf2f(Xb[(size_t)r * FD + f]);
        s1 += v; s2 += v * v;
    }
    __shared__ float l1[256], l2[256];
    l1[threadIdx.x] = s1; l2[threadIdx.x] = s2;
    __syncthreads();
    if (half == 0) {
        atomicAdd(&sums[f], l1[f] + l1[f + 128]);
        atomicAdd(&sumsq[f], l2[f] + l2[f + 128]);
    }
}

// ---------------------------------------------------------------- pooling (sorted graph ids, bf16 in)
__global__ void pool_k(const u16* __restrict__ Xb, const int* __restrict__ gi,
                       float* __restrict__ pooled, int M) {
    int f = threadIdx.x & 127;
    int half = threadIdx.x >> 7;
    int r0 = blockIdx.x * 128 + half;
    int rend = min(blockIdx.x * 128 + 128, M);
    int curg = -1; float acc = 0.f;
    for (int r = r0; r < rend; r += 2) {
        int g = gi[r];
        if (g != curg) {
            if (curg >= 0) atomicAdd(&pooled[(size_t)curg * FD + f], acc);
            curg = g; acc = 0.f;
        }
        acc += bf2f(Xb[(size_t)r * FD + f]);
    }
    if (curg >= 0) atomicAdd(&pooled[(size_t)curg * FD + f], acc);
}

// ---------------------------------------------------------------- fused MLP (one block per graph)
__global__ __launch_bounds__(256) void mlp_k(const float* __restrict__ pooled,
                                             const float* __restrict__ fc1w, const float* __restrict__ fc1b,
                                             const float* __restrict__ fc2w, const float* __restrict__ fc2b,
                                             const float* __restrict__ fc3w, const float* __restrict__ fc3b,
                                             float* __restrict__ out) {
    int g = blockIdx.x, j = threadIdx.x;
    __shared__ float x[128], t1[256], t2[128], p0[128], p1[128];
    if (j < 128) x[j] = pooled[(size_t)g * FD + j];
    __syncthreads();
    float s = fc1b[j];
    for (int k = 0; k < 128; k++) s += x[k] * fc1w[(size_t)k * 256 + j];
    t1[j] = fmaxf(s, 0.f);
    __syncthreads();
    if (j < 128) {
        float s2 = fc2b[j];
        for (int k = 0; k < 256; k++) s2 += t1[k] * fc2w[(size_t)k * 128 + j];
        t2[j] = fmaxf(s2, 0.f);
    }
    __syncthreads();
    if (j < 128) { p0[j] = t2[j] * fc3w[j * 2]; p1[j] = t2[j] * fc3w[j * 2 + 1]; }
    __syncthreads();
    for (int s3 = 64; s3 > 0; s3 >>= 1) {
        if (j < s3) { p0[j] += p0[j + s3]; p1[j] += p1[j + s3]; }
        __syncthreads();
    }
    if (j == 0) { out[g * 2] = p0[0] + fc3b[0]; out[g * 2 + 1] = p1[0] + fc3b[1]; }
}

// ---------------------------------------------------------------- launcher
extern "C" void kernel_launch(void* const* d_in, const int* in_sizes, int n_in,
                              void* d_out, int out_size, void* d_ws, size_t ws_size,
                              hipStream_t stream) {
    const int*   adj  = (const int*)d_in[0];
    const float* xin  = (const float*)d_in[1];
    const int*   gi   = (const int*)d_in[2];
    const float* W1   = (const float*)d_in[4];
    const float* a1   = (const float*)d_in[5];
    const float* bn2g = (const float*)d_in[6];
    const float* bn2b = (const float*)d_in[7];
    const float* W2   = (const float*)d_in[8];
    const float* a2   = (const float*)d_in[9];
    const float* bn3g = (const float*)d_in[10];
    const float* bn3b = (const float*)d_in[11];
    const float* W3   = (const float*)d_in[12];
    const float* a3   = (const float*)d_in[13];
    const float* fc1w = (const float*)d_in[14];
    const float* fc1b = (const float*)d_in[15];
    const float* fc2w = (const float*)d_in[16];
    const float* fc2b = (const float*)d_in[17];
    const float* fc3w = (const float*)d_in[18];
    const float* fc3b = (const float*)d_in[19];
    float* out = (float*)d_out;

    const int N = N_NODES, E = N_EDGES, G = N_GRAPHS;

    u16*   Xb     = (u16*)d_ws;                   // [N,128] bf16 node features
    u16*   Hb     = Xb + (size_t)N * FD;          // [N,128] bf16 post-GEMM
    u16*   Wt     = Hb + (size_t)N * FD;          // [128,128] bf16 transposed, BN-folded
    float* es     = (float*)(Wt + FD * FD);       // [N]
    float* ed     = es + N;                       // [N]
    float* bnbuf  = ed + N;                       // [512]: sumsA, sumsqA, sumsB, sumsqB
    float* sumsA  = bnbuf;
    float* sumsqA = bnbuf + 128;
    float* sumsB  = bnbuf + 256;
    float* sumsqB = bnbuf + 384;
    float* cvec   = bnbuf + 512;                  // [128]
    float* pooled = cvec + FD;                    // [G,128]
    int*   degcnt = (int*)(pooled + (size_t)G * FD); // [N]
    int*   offs   = degcnt + N;                   // [N+1] (padded to N+2)
    int*   cur    = offs + (N + 2);               // [N]
    int*   bsum   = cur + N;                      // [256]
    int*   edst   = bsum + 256;                   // [E] dst per CSR slot

    const int* srcp = adj;
    const int* dstp = adj + E;

    const int NB = (N + 255) / 256;

    // ---- CSR build (once; reused by all 3 layers) — XCD-partitioned
    hipMemsetAsync(degcnt, 0, (size_t)N * sizeof(int), stream);
    count_deg_part_k<<<8 * 392, 256, 0, stream>>>(srcp, degcnt, E);
    scan1_k<<<NB, 256, 0, stream>>>(degcnt, bsum, N, bnbuf, pooled);
    scan3_k<<<NB, 256, 0, stream>>>(degcnt, bsum, offs, cur, N, NB);
    fill_csr_part_k<<<8 * 392, 256, 0, stream>>>(srcp, dstp, cur, edst, E);

    const int gemm_grid = (N + 63) / 64;
    const int wave_grid = (N + 3) / 4;      // 4 waves per 256-thread block
    const float invN = 1.0f / (float)N;

    // ---- layer 1 (fp32 input staged directly; identity affine)
    wprep1_k<<<FD, 128, 0, stream>>>(W1, Wt, cvec);
    gemm_mfma_k<<<gemm_grid, 256, 0, stream>>>(xin, Xb, 1, Wt, cvec, a1, Hb, es, ed, N);
    agg_k<<<wave_grid, 256, 0, stream>>>(Hb, es, ed, offs, edst, Xb, N);
    bnstats_b_k<<<256, 256, 0, stream>>>(Xb, sumsA, sumsqA, N);

    // ---- layer 2 (BN folded into Wt/cvec)
    bnfw_k<<<FD, 128, 0, stream>>>(W2, sumsA, sumsqA, bn2g, bn2b, invN, Wt, cvec);
    gemm_mfma_k<<<gemm_grid, 256, 0, stream>>>(nullptr, Xb, 0, Wt, cvec, a2, Hb, es, ed, N);
    agg_k<<<wave_grid, 256, 0, stream>>>(Hb, es, ed, offs, edst, Xb, N);
    bnstats_b_k<<<256, 256, 0, stream>>>(Xb, sumsB, sumsqB, N);

    // ---- layer 3
    bnfw_k<<<FD, 128, 0, stream>>>(W3, sumsB, sumsqB, bn3g, bn3b, invN, Wt, cvec);
    gemm_mfma_k<<<gemm_grid, 256, 0, stream>>>(nullptr, Xb, 0, Wt, cvec, a3, Hb, es, ed, N);
    agg_k<<<wave_grid, 256, 0, stream>>>(Hb, es, ed, offs, edst, Xb, N);

    // ---- pooling + MLP
    pool_k<<<(N + 127) / 128, 256, 0, stream>>>(Xb, gi, pooled, N);
    mlp_k<<<G, 256, 0, stream>>>(pooled, fc1w, fc1b, fc2w, fc2b, fc3w, fc3b, out);
}

// Round 13
// 432.962 us; speedup vs baseline: 1.6589x; 1.6589x over previous
//
#include <hip/hip_runtime.h>
#include <hip/hip_bf16.h>

#define N_NODES 50000
#define N_EDGES 800000
#define FD 128
#define N_GRAPHS 256
#define NPART 6250   // N_NODES / 8 (nodes per XCD partition)

typedef unsigned short u16;
typedef short bf16x8 __attribute__((ext_vector_type(8)));
typedef float f32x4 __attribute__((ext_vector_type(4)));

__device__ __forceinline__ u16 f2bf(float v) {
    __hip_bfloat16 h = __float2bfloat16(v);
    union { __hip_bfloat16 hh; u16 u; } c; c.hh = h; return c.u;
}
__device__ __forceinline__ float bf2f(u16 r) {
    return __uint_as_float(((unsigned int)r) << 16);
}

// ---------------------------------------------------------------- CSR build (XCD-partitioned)
__global__ __launch_bounds__(256) void count_deg_part_k(const int* __restrict__ src,
                                                        int* __restrict__ cnt, int E) {
    int part = blockIdx.x & 7;
    int lo = part * NPART, hi = lo + NPART;
    int stride = (gridDim.x >> 3) * 256;
    for (int e = (blockIdx.x >> 3) * 256 + threadIdx.x; e < E; e += stride) {
        int s = src[e];
        if (s >= lo && s < hi) atomicAdd(&cnt[s], 1);
    }
}

__global__ __launch_bounds__(256) void fill_csr_part_k(const int* __restrict__ src,
                                                       const int* __restrict__ dst,
                                                       int* __restrict__ cur,
                                                       int* __restrict__ edst, int E) {
    int part = blockIdx.x & 7;
    int lo = part * NPART, hi = lo + NPART;
    int stride = (gridDim.x >> 3) * 256;
    for (int e = (blockIdx.x >> 3) * 256 + threadIdx.x; e < E; e += stride) {
        int s = src[e];
        if (s >= lo && s < hi) {
            int p = atomicAdd(&cur[s], 1);
            edst[p] = dst[e];
        }
    }
}

// per-256-chunk sums; block 0 also zeroes bnbuf (512 f) and pooled (32768 f)
__global__ __launch_bounds__(256) void scan1_k(const int* __restrict__ cnt,
                                               int* __restrict__ bsum, int M,
                                               float* __restrict__ bnbuf,
                                               float* __restrict__ pooled) {
    int i = blockIdx.x * 256 + threadIdx.x;
    int v = (i < M) ? cnt[i] : 0;
    __shared__ int l[256];
    l[threadIdx.x] = v;
    __syncthreads();
    for (int s = 128; s > 0; s >>= 1) {
        if (threadIdx.x < s) l[threadIdx.x] += l[threadIdx.x + s];
        __syncthreads();
    }
    if (threadIdx.x == 0) bsum[blockIdx.x] = l[0];
    if (blockIdx.x == 0) {
        bnbuf[threadIdx.x] = 0.f; bnbuf[threadIdx.x + 256] = 0.f;
        for (int k = threadIdx.x; k < N_GRAPHS * FD; k += 256) pooled[k] = 0.f;
    }
}

// local exclusive scan + redundant per-block scan of raw bsum (merged scan2)
__global__ __launch_bounds__(256) void scan3_k(const int* __restrict__ cnt,
                                               const int* __restrict__ bsum,
                                               int* __restrict__ offs,
                                               int* __restrict__ cur, int M, int NB) {
    int i = blockIdx.x * 256 + threadIdx.x;
    int tid = threadIdx.x;
    __shared__ int bs[256];
    bs[tid] = (tid < NB) ? bsum[tid] : 0;
    __syncthreads();
    for (int off = 1; off < 256; off <<= 1) {
        int t = (tid >= off) ? bs[tid - off] : 0;
        __syncthreads();
        bs[tid] += t;
        __syncthreads();
    }
    int base = (blockIdx.x == 0) ? 0 : bs[blockIdx.x - 1];
    int v = (i < M) ? cnt[i] : 0;
    __shared__ int l[256];
    l[tid] = v;
    __syncthreads();
    for (int off = 1; off < 256; off <<= 1) {
        int t = (tid >= off) ? l[tid - off] : 0;
        __syncthreads();
        l[tid] += t;
        __syncthreads();
    }
    int excl = l[tid] - v + base;
    if (i < M) { offs[i] = excl; cur[i] = excl; }
    if (i == M - 1) offs[M] = excl + v;
}

// ---------------------------------------------------------------- weight prep
// layer 1 (no affine): Wt[n][k] = bf16(W[k][n]); cvec = 0
__global__ __launch_bounds__(128) void wprep1_k(const float* __restrict__ W,
                                                u16* __restrict__ Wt,
                                                float* __restrict__ cvec) {
    int n = blockIdx.x, k = threadIdx.x;
    Wt[(size_t)n * FD + k] = f2bf(W[(size_t)k * FD + n]);
    if (k == 0) cvec[n] = 0.f;
}

// layers 2/3: BN finalize (redundant per block, from sums/sumsq) + weight fold
__global__ __launch_bounds__(128) void bnfw_k(const float* __restrict__ W,
                                              const float* __restrict__ sums,
                                              const float* __restrict__ sumsq,
                                              const float* __restrict__ g,
                                              const float* __restrict__ b,
                                              float invN,
                                              u16* __restrict__ Wt,
                                              float* __restrict__ cvec) {
    int n = blockIdx.x, k = threadIdx.x;
    __shared__ float scs[128], shs[128], l[128];
    float mu = sums[k] * invN;
    float var = sumsq[k] * invN - mu * mu;
    float sc = g[k] * rsqrtf(var + 1e-5f);
    scs[k] = sc;
    shs[k] = b[k] - mu * sc;
    __syncthreads();
    float w = W[(size_t)k * FD + n];
    Wt[(size_t)n * FD + k] = f2bf(scs[k] * w);
    l[k] = shs[k] * w;
    __syncthreads();
    for (int s = 64; s > 0; s >>= 1) {
        if (k < s) l[k] += l[k + s];
        __syncthreads();
    }
    if (k == 0) cvec[n] = l[0];
}

// ---------------------------------------------------------------- MFMA GEMM + dots
__global__ __launch_bounds__(256) void gemm_mfma_k(const float* __restrict__ Xf,
                                                   const u16* __restrict__ Xb,
                                                   int use_f32,
                                                   const u16* __restrict__ Wt,
                                                   const float* __restrict__ cvec,
                                                   const float* __restrict__ avec,
                                                   u16* __restrict__ Hb,
                                                   float* __restrict__ es,
                                                   float* __restrict__ ed, int M) {
    __shared__ u16 As[64][136];   // +8 pad: 2-way bank alias only
    __shared__ u16 Bs[128][136];
    __shared__ float sa_s[128], sa_d[128], cv[128];
    int tid = threadIdx.x;
    if (tid < 128) { sa_s[tid] = avec[tid]; sa_d[tid] = avec[128 + tid]; cv[tid] = cvec[tid]; }
    int row0 = blockIdx.x * 64;
    {
        int n = tid >> 1, k0 = (tid & 1) * 64;
        const uint4* s = (const uint4*)(Wt + (size_t)n * FD + k0);
#pragma unroll
        for (int u = 0; u < 8; u++) *(uint4*)&Bs[n][k0 + u * 8] = s[u];
    }
    {
        int r = tid >> 2, k0 = (tid & 3) * 32;
        int grow = row0 + r;
        if (grow < M) {
            if (use_f32) {
                const float4* s = (const float4*)(Xf + (size_t)grow * FD + k0);
#pragma unroll
                for (int u = 0; u < 8; u++) {
                    float4 v = s[u];
                    ushort4 o;
                    o.x = f2bf(v.x); o.y = f2bf(v.y); o.z = f2bf(v.z); o.w = f2bf(v.w);
                    *(ushort4*)&As[r][k0 + u * 4] = o;
                }
            } else {
                const uint4* s = (const uint4*)(Xb + (size_t)grow * FD + k0);
#pragma unroll
                for (int u = 0; u < 4; u++) *(uint4*)&As[r][k0 + u * 8] = s[u];
            }
        } else {
            uint4 z = make_uint4(0, 0, 0, 0);
#pragma unroll
            for (int u = 0; u < 4; u++) *(uint4*)&As[r][k0 + u * 8] = z;
        }
    }
    __syncthreads();

    int wave = tid >> 6, lane = tid & 63;
    int quad = lane >> 4, n16 = lane & 15;
    int rbase = wave * 16;
    f32x4 acc[8];
    f32x4 zz = {0.f, 0.f, 0.f, 0.f};
#pragma unroll
    for (int t = 0; t < 8; t++) acc[t] = zz;

#pragma unroll
    for (int kk = 0; kk < 128; kk += 32) {
        bf16x8 a = *(const bf16x8*)&As[rbase + n16][kk + quad * 8];
#pragma unroll
        for (int t = 0; t < 8; t++) {
            bf16x8 b = *(const bf16x8*)&Bs[t * 16 + n16][kk + quad * 8];
            acc[t] = __builtin_amdgcn_mfma_f32_16x16x32_bf16(a, b, acc[t], 0, 0, 0);
        }
    }

#pragma unroll
    for (int reg = 0; reg < 4; reg++) {
        int grow = row0 + rbase + quad * 4 + reg;
        float vals[8];
        float ps = 0.f, pd = 0.f;
#pragma unroll
        for (int t = 0; t < 8; t++) {
            float v = acc[t][reg] + cv[t * 16 + n16];
            vals[t] = v;
            ps += v * sa_s[t * 16 + n16];
            pd += v * sa_d[t * 16 + n16];
        }
#pragma unroll
        for (int o = 8; o > 0; o >>= 1) { ps += __shfl_xor(ps, o); pd += __shfl_xor(pd, o); }
        if (grow < M) {
            if (n16 == 0) { es[grow] = ps; ed[grow] = pd; }
#pragma unroll
            for (int t = 0; t < 8; t++)
                Hb[(size_t)grow * FD + t * 16 + n16] = f2bf(vals[t]);
        }
    }
}

// ---------------------------------------------------------------- fused aggregation
// wave per node; 4 edges per 16B-gather instruction (16 lanes x uint4 per edge row);
// ALL locals are named scalars (no addressable arrays -> nothing promoted to LDS).
#define EW(dd) ({ float _ev = esv + ed_[dd]; float _lr = _ev > 0.f ? _ev : 0.2f * _ev; __expf(-_lr); })
#define GACC(rr, ww) do { \
    acc0 += (ww) * __uint_as_float((rr).x << 16); \
    acc1 += (ww) * __uint_as_float((rr).x & 0xffff0000u); \
    acc2 += (ww) * __uint_as_float((rr).y << 16); \
    acc3 += (ww) * __uint_as_float((rr).y & 0xffff0000u); \
    acc4 += (ww) * __uint_as_float((rr).z << 16); \
    acc5 += (ww) * __uint_as_float((rr).z & 0xffff0000u); \
    acc6 += (ww) * __uint_as_float((rr).w << 16); \
    acc7 += (ww) * __uint_as_float((rr).w & 0xffff0000u); } while (0)

__global__ __launch_bounds__(256) void agg_k(const u16* __restrict__ Hb,
                                             const float* __restrict__ es_,
                                             const float* __restrict__ ed_,
                                             const int* __restrict__ offs,
                                             const int* __restrict__ edst,
                                             u16* __restrict__ Out, int M) {
    int node = __builtin_amdgcn_readfirstlane((int)((blockIdx.x * blockDim.x + threadIdx.x) >> 6));
    int lane = threadIdx.x & 63;
    if (node >= M) return;
    int g = lane >> 4;      // edge slot 0..3
    int p = lane & 15;      // feature octet
    int s0 = offs[node], s1 = offs[node + 1];
    float esv = es_[node];
    const uint4* Hq = (const uint4*)Hb;     // row = 16 x uint4 (256 B)
    float acc0 = 0.f, acc1 = 0.f, acc2 = 0.f, acc3 = 0.f;
    float acc4 = 0.f, acc5 = 0.f, acc6 = 0.f, acc7 = 0.f;
    float rs = 0.f;
    int e = s0;
    for (; e + 8 <= s1; e += 8) {
        int d0 = __builtin_amdgcn_readfirstlane(edst[e]);
        int d1 = __builtin_amdgcn_readfirstlane(edst[e + 1]);
        int d2 = __builtin_amdgcn_readfirstlane(edst[e + 2]);
        int d3 = __builtin_amdgcn_readfirstlane(edst[e + 3]);
        int d4 = __builtin_amdgcn_readfirstlane(edst[e + 4]);
        int d5 = __builtin_amdgcn_readfirstlane(edst[e + 5]);
        int d6 = __builtin_amdgcn_readfirstlane(edst[e + 6]);
        int d7 = __builtin_amdgcn_readfirstlane(edst[e + 7]);
        int dgA = g == 0 ? d0 : (g == 1 ? d1 : (g == 2 ? d2 : d3));
        int dgB = g == 0 ? d4 : (g == 1 ? d5 : (g == 2 ? d6 : d7));
        uint4 rA = Hq[(size_t)dgA * 16 + p];
        uint4 rB = Hq[(size_t)dgB * 16 + p];
        float w0 = EW(d0), w1 = EW(d1), w2 = EW(d2), w3 = EW(d3);
        float w4 = EW(d4), w5 = EW(d5), w6 = EW(d6), w7 = EW(d7);
        rs += w0 + w1 + w2 + w3 + w4 + w5 + w6 + w7;
        float wgA = g == 0 ? w0 : (g == 1 ? w1 : (g == 2 ? w2 : w3));
        float wgB = g == 0 ? w4 : (g == 1 ? w5 : (g == 2 ? w6 : w7));
        GACC(rA, wgA);
        GACC(rB, wgB);
    }
    while (e < s1) {
        int m = s1 - e;                      // 1..7 remaining; take up to 4
        if (m > 4) m = 4;
        int d0 = __builtin_amdgcn_readfirstlane(edst[e]);
        int d1 = m > 1 ? __builtin_amdgcn_readfirstlane(edst[e + 1]) : d0;
        int d2 = m > 2 ? __builtin_amdgcn_readfirstlane(edst[e + 2]) : d0;
        int d3 = m > 3 ? __builtin_amdgcn_readfirstlane(edst[e + 3]) : d0;
        float w0 = EW(d0);
        float w1 = m > 1 ? EW(d1) : 0.f;
        float w2 = m > 2 ? EW(d2) : 0.f;
        float w3 = m > 3 ? EW(d3) : 0.f;
        rs += w0 + w1 + w2 + w3;
        int dgA = g == 0 ? d0 : (g == 1 ? d1 : (g == 2 ? d2 : d3));
        float wgA = g == 0 ? w0 : (g == 1 ? w1 : (g == 2 ? w2 : w3));
        uint4 rA = Hq[(size_t)dgA * 16 + p];
        GACC(rA, wgA);
        e += m;
    }
    // combine the 4 edge-groups (lanes xor 16, 32 hold same features)
#pragma unroll
    for (int o = 16; o < 64; o <<= 1) {
        acc0 += __shfl_xor(acc0, o); acc1 += __shfl_xor(acc1, o);
        acc2 += __shfl_xor(acc2, o); acc3 += __shfl_xor(acc3, o);
        acc4 += __shfl_xor(acc4, o); acc5 += __shfl_xor(acc5, o);
        acc6 += __shfl_xor(acc6, o); acc7 += __shfl_xor(acc7, o);
    }
    if (g == 0) {
        float inv = 1.f / (rs + 1e-16f);
        float v0 = acc0 * inv, v1 = acc1 * inv, v2 = acc2 * inv, v3 = acc3 * inv;
        float v4 = acc4 * inv, v5 = acc5 * inv, v6 = acc6 * inv, v7 = acc7 * inv;
        v0 = v0 > 0.f ? v0 : (__expf(v0) - 1.f);
        v1 = v1 > 0.f ? v1 : (__expf(v1) - 1.f);
        v2 = v2 > 0.f ? v2 : (__expf(v2) - 1.f);
        v3 = v3 > 0.f ? v3 : (__expf(v3) - 1.f);
        v4 = v4 > 0.f ? v4 : (__expf(v4) - 1.f);
        v5 = v5 > 0.f ? v5 : (__expf(v5) - 1.f);
        v6 = v6 > 0.f ? v6 : (__expf(v6) - 1.f);
        v7 = v7 > 0.f ? v7 : (__expf(v7) - 1.f);
        uint4 o4;
        o4.x = ((unsigned int)f2bf(v1) << 16) | f2bf(v0);
        o4.y = ((unsigned int)f2bf(v3) << 16) | f2bf(v2);
        o4.z = ((unsigned int)f2bf(v5) << 16) | f2bf(v4);
        o4.w = ((unsigned int)f2bf(v7) << 16) | f2bf(v6);
        ((uint4*)Out)[(size_t)node * 16 + p] = o4;
    }
}

// ---------------------------------------------------------------- BN stats (bf16 input)
__global__ void bnstats_b_k(const u16* __restrict__ Xb, float* __restrict__ sums,
                            float* __restrict__ sumsq, int M) {
    int f = threadIdx.x & 127;
    int half = threadIdx.x >> 7;
    float s1 = 0.f, s2 = 0.f;
    for (int r = blockIdx.x * 2 + half; r < M; r += gridDim.x * 2) {
        float v = bf2f(Xb[(size_t)r * FD + f]);
        s1 += v; s2 += v * v;
    }
    __shared__ float l1[256], l2[256];
    l1[threadIdx.x] = s1; l2[threadIdx.x] = s2;
    __syncthreads();
    if (half == 0) {
        atomicAdd(&sums[f], l1[f] + l1[f + 128]);
        atomicAdd(&sumsq[f], l2[f] + l2[f + 128]);
    }
}

// ---------------------------------------------------------------- pooling (sorted graph ids, bf16 in)
__global__ void pool_k(const u16* __restrict__ Xb, const int* __restrict__ gi,
                       float* __restrict__ pooled, int M) {
    int f = threadIdx.x & 127;
    int half = threadIdx.x >> 7;
    int r0 = blockIdx.x * 128 + half;
    int rend = min(blockIdx.x * 128 + 128, M);
    int curg = -1; float acc = 0.f;
    for (int r = r0; r < rend; r += 2) {
        int g = gi[r];
        if (g != curg) {
            if (curg >= 0) atomicAdd(&pooled[(size_t)curg * FD + f], acc);
            curg = g; acc = 0.f;
        }
        acc += bf2f(Xb[(size_t)r * FD + f]);
    }
    if (curg >= 0) atomicAdd(&pooled[(size_t)curg * FD + f], acc);
}

// ---------------------------------------------------------------- fused MLP (one block per graph)
__global__ __launch_bounds__(256) void mlp_k(const float* __restrict__ pooled,
                                             const float* __restrict__ fc1w, const float* __restrict__ fc1b,
                                             const float* __restrict__ fc2w, const float* __restrict__ fc2b,
                                             const float* __restrict__ fc3w, const float* __restrict__ fc3b,
                                             float* __restrict__ out) {
    int g = blockIdx.x, j = threadIdx.x;
    __shared__ float x[128], t1[256], t2[128], p0[128], p1[128];
    if (j < 128) x[j] = pooled[(size_t)g * FD + j];
    __syncthreads();
    float s = fc1b[j];
    for (int k = 0; k < 128; k++) s += x[k] * fc1w[(size_t)k * 256 + j];
    t1[j] = fmaxf(s, 0.f);
    __syncthreads();
    if (j < 128) {
        float s2 = fc2b[j];
        for (int k = 0; k < 256; k++) s2 += t1[k] * fc2w[(size_t)k * 128 + j];
        t2[j] = fmaxf(s2, 0.f);
    }
    __syncthreads();
    if (j < 128) { p0[j] = t2[j] * fc3w[j * 2]; p1[j] = t2[j] * fc3w[j * 2 + 1]; }
    __syncthreads();
    for (int s3 = 64; s3 > 0; s3 >>= 1) {
        if (j < s3) { p0[j] += p0[j + s3]; p1[j] += p1[j + s3]; }
        __syncthreads();
    }
    if (j == 0) { out[g * 2] = p0[0] + fc3b[0]; out[g * 2 + 1] = p1[0] + fc3b[1]; }
}

// ---------------------------------------------------------------- launcher
extern "C" void kernel_launch(void* const* d_in, const int* in_sizes, int n_in,
                              void* d_out, int out_size, void* d_ws, size_t ws_size,
                              hipStream_t stream) {
    const int*   adj  = (const int*)d_in[0];
    const float* xin  = (const float*)d_in[1];
    const int*   gi   = (const int*)d_in[2];
    const float* W1   = (const float*)d_in[4];
    const float* a1   = (const float*)d_in[5];
    const float* bn2g = (const float*)d_in[6];
    const float* bn2b = (const float*)d_in[7];
    const float* W2   = (const float*)d_in[8];
    const float* a2   = (const float*)d_in[9];
    const float* bn3g = (const float*)d_in[10];
    const float* bn3b = (const float*)d_in[11];
    const float* W3   = (const float*)d_in[12];
    const float* a3   = (const float*)d_in[13];
    const float* fc1w = (const float*)d_in[14];
    const float* fc1b = (const float*)d_in[15];
    const float* fc2w = (const float*)d_in[16];
    const float* fc2b = (const float*)d_in[17];
    const float* fc3w = (const float*)d_in[18];
    const float* fc3b = (const float*)d_in[19];
    float* out = (float*)d_out;

    const int N = N_NODES, E = N_EDGES, G = N_GRAPHS;

    u16*   Xb     = (u16*)d_ws;                   // [N,128] bf16 node features
    u16*   Hb     = Xb + (size_t)N * FD;          // [N,128] bf16 post-GEMM
    u16*   Wt     = Hb + (size_t)N * FD;          // [128,128] bf16 transposed, BN-folded
    float* es     = (float*)(Wt + FD * FD);       // [N]
    float* ed     = es + N;                       // [N]
    float* bnbuf  = ed + N;                       // [512]: sumsA, sumsqA, sumsB, sumsqB
    float* sumsA  = bnbuf;
    float* sumsqA = bnbuf + 128;
    float* sumsB  = bnbuf + 256;
    float* sumsqB = bnbuf + 384;
    float* cvec   = bnbuf + 512;                  // [128]
    float* pooled = cvec + FD;                    // [G,128]
    int*   degcnt = (int*)(pooled + (size_t)G * FD); // [N]
    int*   offs   = degcnt + N;                   // [N+1] (padded to N+2)
    int*   cur    = offs + (N + 2);               // [N]
    int*   bsum   = cur + N;                      // [256]
    int*   edst   = bsum + 256;                   // [E] dst per CSR slot

    const int* srcp = adj;
    const int* dstp = adj + E;

    const int NB = (N + 255) / 256;

    // ---- CSR build (once; reused by all 3 layers) — XCD-partitioned
    hipMemsetAsync(degcnt, 0, (size_t)N * sizeof(int), stream);
    count_deg_part_k<<<8 * 392, 256, 0, stream>>>(srcp, degcnt, E);
    scan1_k<<<NB, 256, 0, stream>>>(degcnt, bsum, N, bnbuf, pooled);
    scan3_k<<<NB, 256, 0, stream>>>(degcnt, bsum, offs, cur, N, NB);
    fill_csr_part_k<<<8 * 392, 256, 0, stream>>>(srcp, dstp, cur, edst, E);

    const int gemm_grid = (N + 63) / 64;
    const int wave_grid = (N + 3) / 4;      // 4 waves per 256-thread block
    const float invN = 1.0f / (float)N;

    // ---- layer 1 (fp32 input staged directly; identity affine)
    wprep1_k<<<FD, 128, 0, stream>>>(W1, Wt, cvec);
    gemm_mfma_k<<<gemm_grid, 256, 0, stream>>>(xin, Xb, 1, Wt, cvec, a1, Hb, es, ed, N);
    agg_k<<<wave_grid, 256, 0, stream>>>(Hb, es, ed, offs, edst, Xb, N);
    bnstats_b_k<<<256, 256, 0, stream>>>(Xb, sumsA, sumsqA, N);

    // ---- layer 2 (BN folded into Wt/cvec)
    bnfw_k<<<FD, 128, 0, stream>>>(W2, sumsA, sumsqA, bn2g, bn2b, invN, Wt, cvec);
    gemm_mfma_k<<<gemm_grid, 256, 0, stream>>>(nullptr, Xb, 0, Wt, cvec, a2, Hb, es, ed, N);
    agg_k<<<wave_grid, 256, 0, stream>>>(Hb, es, ed, offs, edst, Xb, N);
    bnstats_b_k<<<256, 256, 0, stream>>>(Xb, sumsB, sumsqB, N);

    // ---- layer 3
    bnfw_k<<<FD, 128, 0, stream>>>(W3, sumsB, sumsqB, bn3g, bn3b, invN, Wt, cvec);
    gemm_mfma_k<<<gemm_grid, 256, 0, stream>>>(nullptr, Xb, 0, Wt, cvec, a3, Hb, es, ed, N);
    agg_k<<<wave_grid, 256, 0, stream>>>(Hb, es, ed, offs, edst, Xb, N);

    // ---- pooling + MLP
    pool_k<<<(N + 127) / 128, 256, 0, stream>>>(Xb, gi, pooled, N);
    mlp_k<<<G, 256, 0, stream>>>(pooled, fc1w, fc1b, fc2w, fc2b, fc3w, fc3b, out);
}